// Round 2
// baseline (1093.812 us; speedup 1.0000x reference)
//
#include <hip/hip_runtime.h>

#define BB 4
#define CY 256
#define CM 128
#define HW 4096       // 64*64
#define HWy 1024      // 32*32
#define PHW 4356      // 66*66
#define EPSF 1e-5f
#define TWOPI 6.2831853071795864769f

// ---------------- conv kernels ----------------

__global__ void conv1_kernel(const float* __restrict__ y, const float* __restrict__ w,
                             const float* __restrict__ g, const float* __restrict__ bb,
                             const float* __restrict__ m, const float* __restrict__ v,
                             float* __restrict__ y1){
  int p = blockIdx.x*256 + threadIdx.x;   // 0..1023
  int ocb = blockIdx.y*8;
  int b = blockIdx.z;
  float acc[8] = {0,0,0,0,0,0,0,0};
  const float* yb = y + (size_t)b*CY*HWy + p;
  #pragma unroll 4
  for(int ic=0; ic<CY; ic++){
    float xv = yb[(size_t)ic*HWy];
    #pragma unroll
    for(int j=0;j<8;j++) acc[j] += xv * w[(ocb+j)*CY + ic];
  }
  #pragma unroll
  for(int j=0;j<8;j++){
    int oc = ocb+j;
    float s = g[oc]*rsqrtf(v[oc]+EPSF);
    float bi = bb[oc] - m[oc]*s;
    float r = acc[j]*s + bi;
    y1[((size_t)(b*CM+oc))*HWy + p] = r>0.f?r:0.f;
  }
}

__global__ void kvconv_kernel(const float* __restrict__ x, const float* __restrict__ kw,
                              const float* __restrict__ vw,
                              float* __restrict__ k, float* __restrict__ v){
  int p = blockIdx.x*256 + threadIdx.x;  // 0..4355 (guard)
  int ocb = blockIdx.y*8; int b = blockIdx.z;
  if(p >= PHW) return;
  int hh = p/66, ww2 = p - hh*66;
  int ih = hh-1, iw = ww2-1;
  bool inb = (ih>=0 && ih<64 && iw>=0 && iw<64);
  float acck[8] = {0,0,0,0,0,0,0,0};
  float accv[8] = {0,0,0,0,0,0,0,0};
  if(inb){
    const float* xb = x + (size_t)b*CM*HW + ih*64 + iw;
    #pragma unroll 4
    for(int ic=0; ic<CM; ic++){
      float xv = xb[(size_t)ic*HW];
      #pragma unroll
      for(int j=0;j<8;j++){ acck[j] += xv*kw[(ocb+j)*CM+ic]; accv[j] += xv*vw[(ocb+j)*CM+ic]; }
    }
  }
  #pragma unroll
  for(int j=0;j<8;j++){
    size_t o = ((size_t)(b*CM+ocb+j))*PHW + p;
    k[o]=acck[j]; v[o]=accv[j];
  }
}

// ---------------- attention (q-conv fused) ----------------

__global__ void attn_kernel(const float* __restrict__ y1, const float* __restrict__ qw,
                            const float* __restrict__ k, const float* __restrict__ v,
                            const float* __restrict__ relh, const float* __restrict__ relw,
                            float* __restrict__ xatt){
  int t = blockIdx.x*256 + threadIdx.x;  // over B*CM*HW
  int p = t & 4095;
  int bc = t >> 12;       // b*128+c
  int c = bc & 127;
  int b = bc >> 7;
  int h = p>>6, w2 = p&63;
  // fused q = conv1x1(y_up, q_w) at this (b,c,p)
  int mi = ((p>>7)<<5) + ((p&63)>>1);    // (h/2)*32 + w/2
  const float* yb = y1 + (size_t)b*CM*HWy + mi;
  const float* wq = qw + c*CM;           // uniform per wave -> scalar loads
  float qv = 0.f;
  #pragma unroll 4
  for(int ic=0; ic<CM; ic++) qv += yb[(size_t)ic*HWy] * wq[ic];

  const float* kb = k + (size_t)bc*PHW;
  const float* vb = v + (size_t)bc*PHW;
  float lg[9], vv[9];
  #pragma unroll
  for(int ti=0; ti<3; ti++){
    #pragma unroll
    for(int tj=0; tj<3; tj++){
      int idx = (h+ti)*66 + (w2+tj);
      float rel = (c<64) ? relh[c*3+ti] : relw[(c-64)*3+tj];
      float kv = kb[idx] + rel;
      lg[ti*3+tj] = qv*kv;
      vv[ti*3+tj] = vb[idx];
    }
  }
  float mx = lg[0];
  #pragma unroll
  for(int i=1;i<9;i++) mx = fmaxf(mx, lg[i]);
  float s=0.f, o=0.f;
  #pragma unroll
  for(int i=0;i<9;i++){ float e = __expf(lg[i]-mx); s += e; o += e*vv[i]; }
  xatt[t] = o/s;
}

// ---------------- FFT helpers ----------------

template<int SIGN>
__device__ inline void dft8(const float2* a, float2* X){
  constexpr float C8[8] = {1.f,0.70710678118654752f,0.f,-0.70710678118654752f,
                           -1.f,-0.70710678118654752f,0.f,0.70710678118654752f};
  constexpr float S8[8] = {0.f,0.70710678118654752f,1.f,0.70710678118654752f,
                           0.f,-0.70710678118654752f,-1.f,-0.70710678118654752f};
  #pragma unroll
  for(int kk=0;kk<8;kk++){
    float xr=0.f, xi=0.f;
    #pragma unroll
    for(int n=0;n<8;n++){
      const int j=(n*kk)&7;
      const float wr = C8[j];
      const float wi = SIGN*S8[j];   // e^{SIGN*2pi i j/8}
      xr += a[n].x*wr - a[n].y*wi;
      xi += a[n].x*wi + a[n].y*wr;
    }
    X[kk].x=xr; X[kk].y=xi;
  }
}

// 64 lines x 64 elems, in-place in LDS. line l at img+l*lineStride, elem e at +e*elemStride.
// 8 threads per line (j), 32 lines per half-pass.
template<int SIGN>
__device__ inline void fft64_lds(float2* img, int lineStride, int elemStride){
  int j  = threadIdx.x >> 5;   // 0..7
  int ll = threadIdx.x & 31;
  #pragma unroll
  for(int half=0; half<2; half++){
    float2* L = img + (half*32 + ll)*lineStride;
    float2 a[8];
    #pragma unroll
    for(int n1=0;n1<8;n1++) a[n1] = L[(n1*8+j)*elemStride];
    float2 A[8];
    dft8<SIGN>(a, A);
    __syncthreads();           // all reads done before overwrite
    #pragma unroll
    for(int k1=0;k1<8;k1++){
      float ang = SIGN * (TWOPI/64.f) * (float)(j*k1);
      float sn, cs; __sincosf(ang, &sn, &cs);
      L[(k1*8+j)*elemStride] = make_float2(A[k1].x*cs - A[k1].y*sn, A[k1].x*sn + A[k1].y*cs);
    }
    __syncthreads();
    float2 bv[8];
    #pragma unroll
    for(int n2=0;n2<8;n2++) bv[n2] = L[(j*8+n2)*elemStride];
    float2 Y[8];
    dft8<SIGN>(bv, Y);
    __syncthreads();
    #pragma unroll
    for(int k2=0;k2<8;k2++) L[(j + 8*k2)*elemStride] = Y[k2];
    __syncthreads();
  }
}

// whole-image forward 2D FFT: real xatt (64x64) -> complex E, scale 1/64. One block per (b,c).
__global__ void fft2d_fwd(const float* __restrict__ xatt, float2* __restrict__ E){
  __shared__ float2 img[64*65];
  int bc = blockIdx.x;
  const float* src = xatt + (size_t)bc*HW;
  for(int s=threadIdx.x; s<1024; s+=256){
    float4 t = ((const float4*)src)[s];
    int idx = s*4; int r = idx>>6, c = idx&63;
    float2* d = img + r*65 + c;
    d[0]=make_float2(t.x,0.f); d[1]=make_float2(t.y,0.f);
    d[2]=make_float2(t.z,0.f); d[3]=make_float2(t.w,0.f);
  }
  __syncthreads();
  fft64_lds<-1>(img, 65, 1);   // rows
  fft64_lds<-1>(img, 1, 65);   // cols
  float2* dst = E + (size_t)bc*HW;
  for(int s=threadIdx.x; s<2048; s+=256){
    int idx = s*2; int r = idx>>6, c = idx&63;
    float2 v0 = img[r*65+c], v1 = img[r*65+c+1];
    ((float4*)dst)[s] = make_float4(v0.x*0.015625f, v0.y*0.015625f, v1.x*0.015625f, v1.y*0.015625f);
  }
}

// whole-image inverse 2D FFT: complex F -> real G, scale 1/64. One block per (kb,o).
__global__ void fft2d_inv(const float2* __restrict__ F, float* __restrict__ G){
  __shared__ float2 img[64*65];
  int bc = blockIdx.x;
  const float2* src = F + (size_t)bc*HW;
  for(int s=threadIdx.x; s<2048; s+=256){
    float4 t = ((const float4*)src)[s];
    int idx = s*2; int r = idx>>6, c = idx&63;
    img[r*65+c]   = make_float2(t.x,t.y);
    img[r*65+c+1] = make_float2(t.z,t.w);
  }
  __syncthreads();
  fft64_lds<1>(img, 65, 1);
  fft64_lds<1>(img, 1, 65);
  float* dst = G + (size_t)bc*HW;
  for(int s=threadIdx.x; s<1024; s+=256){
    int idx = s*4; int r = idx>>6, c = idx&63;
    float2* p2 = img + r*65 + c;
    ((float4*)dst)[s] = make_float4(p2[0].x*0.015625f, p2[1].x*0.015625f,
                                    p2[2].x*0.015625f, p2[3].x*0.015625f);
  }
}

// 128-pt FFT along channel axis, in-place; 16 lines/block x 16 threads
template<int SIGN>
__global__ void fft128_kernel(float* data, float scale){
  __shared__ float2 tmp[16][129];
  int ll = threadIdx.x & 15;
  int j  = threadIdx.x >> 4;   // n2 = 0..15
  int l = blockIdx.x*16 + ll;  // (b, hf*64+wf)
  int b = l >> 12;
  int rem = l & 4095;
  size_t base = (size_t)b*CM*HW + rem;
  float2* cd = (float2*)data;
  float2 a[8];
  #pragma unroll
  for(int n1=0;n1<8;n1++) a[n1] = cd[base + (size_t)(16*n1 + j)*HW];
  float2 A[8];
  dft8<SIGN>(a, A);
  #pragma unroll
  for(int k1=0;k1<8;k1++){
    float ang = SIGN*(TWOPI/128.f)*(float)(j*k1);
    float sn,cs; __sincosf(ang,&sn,&cs);
    tmp[ll][k1*16 + j] = make_float2(A[k1].x*cs - A[k1].y*sn, A[k1].x*sn + A[k1].y*cs);
  }
  __syncthreads();
  int k1 = j & 7, half = j >> 3;
  float2 bv[16];
  #pragma unroll
  for(int n2=0;n2<16;n2++) bv[n2] = tmp[ll][k1*16+n2];
  #pragma unroll
  for(int kk=0;kk<8;kk++){
    int k2 = half*8 + kk;
    float xr=0.f, xi=0.f;
    #pragma unroll
    for(int n2=0;n2<16;n2++){
      float ang = SIGN*(TWOPI/16.f)*(float)((n2*k2)&15);
      float sn,cs; __sincosf(ang,&sn,&cs);
      xr += bv[n2].x*cs - bv[n2].y*sn;
      xi += bv[n2].x*sn + bv[n2].y*cs;
    }
    cd[base + (size_t)(k1 + 8*k2)*HW] = make_float2(xr*scale, xi*scale);
  }
}

// ---------------- channel-mixing einsum (+inline batch FFT4 + mask) ----------------
// OutF[kb,o,f] = sum_i FFT4_b(E[b,i,f])[kb] * w1[i,o,f]
__global__ void einsum_kernel(const float2* __restrict__ Xf, const float* __restrict__ w1r,
                              const float* __restrict__ w1i, float2* __restrict__ OutF){
  int fl = threadIdx.x & 15;      // 16 f-groups of 4 f -> f-tile 64
  int ol = threadIdx.x >> 4;      // 0..15 o within tile
  int obase = blockIdx.x * 16;
  int fbase = blockIdx.y * 64;
  __shared__ float2 Xs[8][4][64]; // [ii][kb][f], 16 KB
  float accr[4][4], acci[4][4];   // [ff][kb]
  #pragma unroll
  for(int a1=0;a1<4;a1++)
    #pragma unroll
    for(int a2=0;a2<4;a2++){ accr[a1][a2]=0.f; acci[a1][a2]=0.f; }

  for(int ic=0; ic<CM; ic+=8){
    __syncthreads();
    #pragma unroll
    for(int s=threadIdx.x; s<512; s+=256){
      int ii = s>>6, fo = s&63;
      size_t base = ((size_t)(ic+ii))*HW + fbase + fo;
      float2 x0 = Xf[base];
      float2 x1 = Xf[base +  524288];
      float2 x2 = Xf[base + 1048576];
      float2 x3 = Xf[base + 1572864];
      Xs[ii][0][fo] = make_float2(x0.x+x1.x+x2.x+x3.x,       x0.y+x1.y+x2.y+x3.y);
      Xs[ii][1][fo] = make_float2(x0.x+x1.y-x2.x-x3.y,       x0.y-x1.x-x2.y+x3.x);
      Xs[ii][2][fo] = make_float2(x0.x-x1.x+x2.x-x3.x,       x0.y-x1.y+x2.y-x3.y);
      Xs[ii][3][fo] = make_float2(x0.x-x1.y-x2.x+x3.y,       x0.y+x1.x-x2.y-x3.x);
    }
    __syncthreads();
    #pragma unroll
    for(int ii=0; ii<8; ii++){
      size_t wbase = ((size_t)((ic+ii)*CM + obase + ol))*HW + fbase + fl*4;
      float4 wr = *(const float4*)(w1r + wbase);
      float4 wi = *(const float4*)(w1i + wbase);
      #pragma unroll
      for(int kb=0; kb<4; kb++){
        const float4* xp = (const float4*)&Xs[ii][kb][0];
        float4 xa = xp[fl*2], xb = xp[fl*2+1];
        accr[0][kb] += xa.x*wr.x - xa.y*wi.x;  acci[0][kb] += xa.x*wi.x + xa.y*wr.x;
        accr[1][kb] += xa.z*wr.y - xa.w*wi.y;  acci[1][kb] += xa.z*wi.y + xa.w*wr.y;
        accr[2][kb] += xb.x*wr.z - xb.y*wi.z;  acci[2][kb] += xb.x*wi.z + xb.y*wr.z;
        accr[3][kb] += xb.z*wr.w - xb.w*wi.w;  acci[3][kb] += xb.z*wi.w + xb.w*wr.w;
      }
    }
  }
  // mask + packed writes (32B contiguous per (kb))
  int f0 = fbase + fl*4;
  float msk[4];
  #pragma unroll
  for(int ff=0; ff<4; ff++){
    int f = f0+ff, hf = f>>6, wf = f&63;
    msk[ff] = ((hf<3||hf>60)&&(wf<3||wf>60)) ? 0.f : 1.f;
  }
  int o = obase + ol;
  #pragma unroll
  for(int kb=0; kb<4; kb++){
    float4* dst = (float4*)(OutF + ((size_t)(kb*CM+o))*HW + f0);
    dst[0] = make_float4(accr[0][kb]*msk[0], acci[0][kb]*msk[0],
                         accr[1][kb]*msk[1], acci[1][kb]*msk[1]);
    dst[1] = make_float4(accr[2][kb]*msk[2], acci[2][kb]*msk[2],
                         accr[3][kb]*msk[3], acci[3][kb]*msk[3]);
  }
}

// ---------------- final combine: w0 conv + blend + bn2 + relu ----------------
__global__ void final_kernel(const float* __restrict__ G, const float* __restrict__ xatt,
                             const float* __restrict__ w0, const float* __restrict__ w0b,
                             const float* __restrict__ r1p, const float* __restrict__ r2p,
                             const float* __restrict__ g2, const float* __restrict__ b2,
                             const float* __restrict__ m2, const float* __restrict__ v2,
                             float* __restrict__ yout){
  int p = blockIdx.x*256 + threadIdx.x;  // 0..4095
  int ocb = blockIdx.y*8; int b = blockIdx.z;
  float r1 = r1p[0], r2 = r2p[0];
  float acc[8] = {0,0,0,0,0,0,0,0};
  const float* xb = xatt + (size_t)b*CM*HW + p;
  #pragma unroll 4
  for(int ic=0; ic<CM; ic++){
    float xv = xb[(size_t)ic*HW];
    #pragma unroll
    for(int j=0;j<8;j++) acc[j] += xv * w0[(ocb+j)*CM + ic];
  }
  #pragma unroll
  for(int j=0;j<8;j++){
    int oc = ocb+j;
    float fam = r1 * G[((size_t)(b*CM+oc))*HW + p] + r2*(acc[j] + w0b[oc]);
    float s = g2[oc]*rsqrtf(v2[oc]+EPSF);
    float bi = b2[oc] - m2[oc]*s;
    float val = fam*s + bi;
    yout[((size_t)(b*CM+oc))*HW + p] = val>0.f?val:0.f;
  }
}

extern "C" void kernel_launch(void* const* d_in, const int* in_sizes, int n_in,
                              void* d_out, int out_size, void* d_ws, size_t ws_size,
                              hipStream_t stream){
  const float* x       = (const float*)d_in[0];
  const float* y       = (const float*)d_in[1];
  const float* conv1_w = (const float*)d_in[2];
  const float* bn1_g   = (const float*)d_in[3];
  const float* bn1_b   = (const float*)d_in[4];
  const float* bn1_m   = (const float*)d_in[5];
  const float* bn1_v   = (const float*)d_in[6];
  const float* q_w     = (const float*)d_in[7];
  const float* k_w     = (const float*)d_in[8];
  const float* v_w     = (const float*)d_in[9];
  const float* rel_h   = (const float*)d_in[10];
  const float* rel_w   = (const float*)d_in[11];
  const float* rate1   = (const float*)d_in[12];
  const float* rate2   = (const float*)d_in[13];
  const float* w1r     = (const float*)d_in[14];
  const float* w1i     = (const float*)d_in[15];
  const float* w0_w    = (const float*)d_in[16];
  const float* w0_b    = (const float*)d_in[17];
  const float* bn2_g   = (const float*)d_in[18];
  const float* bn2_b   = (const float*)d_in[19];
  const float* bn2_m   = (const float*)d_in[20];
  const float* bn2_v   = (const float*)d_in[21];
  (void)in_sizes; (void)n_in; (void)out_size; (void)ws_size;

  char* ws = (char*)d_ws;
  // phase-1 (dead after attn)
  float* Y1 = (float*)(ws + 0);                 // 2 MB
  float* K  = (float*)(ws + 2097152);           // 8.92 MB
  float* V  = (float*)(ws + 11018240);          // 8.92 MB
  // phase-2
  float2* E = (float2*)(ws + 0);                // 16 MB (written after attn completes)
  float2* F = (float2*)(ws + 16777216);         // 16 MB  -> peak ws = 32 MB
  float*  G = (float*)(ws + 0);                 // 8 MB over dead E

  float* yout = (float*)d_out;
  float* xatt = (float*)d_out + 2097152;

  conv1_kernel<<<dim3(4,16,BB),256,0,stream>>>(y, conv1_w, bn1_g,bn1_b,bn1_m,bn1_v, Y1);
  kvconv_kernel<<<dim3(18,16,BB),256,0,stream>>>(x, k_w, v_w, K, V);
  attn_kernel<<<dim3(8192),256,0,stream>>>(Y1, q_w, K, V, rel_h, rel_w, xatt);

  fft2d_fwd<<<dim3(512),256,0,stream>>>(xatt, E);
  fft128_kernel<-1><<<dim3(1024),256,0,stream>>>((float*)E, 0.044194173824159216f);
  einsum_kernel<<<dim3(8,64),256,0,stream>>>(E, w1r, w1i, F);
  fft2d_inv<<<dim3(512),256,0,stream>>>(F, G);

  final_kernel<<<dim3(16,16,BB),256,0,stream>>>(G, xatt, w0_w, w0_b, rate1, rate2,
                                                bn2_g,bn2_b,bn2_m,bn2_v, yout);
}

// Round 3
// 800.213 us; speedup vs baseline: 1.3669x; 1.3669x over previous
//
#include <hip/hip_runtime.h>

#define BB 4
#define CY 256
#define CM 128
#define HW 4096       // 64*64
#define HWy 1024      // 32*32
#define PHW 4356      // 66*66
#define EPSF 1e-5f
#define TWOPI 6.2831853071795864769f

// ---------------- conv kernels ----------------

__global__ void conv1_kernel(const float* __restrict__ y, const float* __restrict__ w,
                             const float* __restrict__ g, const float* __restrict__ bb,
                             const float* __restrict__ m, const float* __restrict__ v,
                             float* __restrict__ y1){
  int p = blockIdx.x*256 + threadIdx.x;   // 0..1023
  int ocb = blockIdx.y*8;
  int b = blockIdx.z;
  float acc[8] = {0,0,0,0,0,0,0,0};
  const float* yb = y + (size_t)b*CY*HWy + p;
  #pragma unroll 4
  for(int ic=0; ic<CY; ic++){
    float xv = yb[(size_t)ic*HWy];
    #pragma unroll
    for(int j=0;j<8;j++) acc[j] += xv * w[(ocb+j)*CY + ic];
  }
  #pragma unroll
  for(int j=0;j<8;j++){
    int oc = ocb+j;
    float s = g[oc]*rsqrtf(v[oc]+EPSF);
    float bi = bb[oc] - m[oc]*s;
    float r = acc[j]*s + bi;
    y1[((size_t)(b*CM+oc))*HWy + p] = r>0.f?r:0.f;
  }
}

__global__ void kvconv_kernel(const float* __restrict__ x, const float* __restrict__ kw,
                              const float* __restrict__ vw,
                              float* __restrict__ k, float* __restrict__ v){
  int p = blockIdx.x*256 + threadIdx.x;  // 0..4355 (guard)
  int ocb = blockIdx.y*8; int b = blockIdx.z;
  if(p >= PHW) return;
  int hh = p/66, ww2 = p - hh*66;
  int ih = hh-1, iw = ww2-1;
  bool inb = (ih>=0 && ih<64 && iw>=0 && iw<64);
  float acck[8] = {0,0,0,0,0,0,0,0};
  float accv[8] = {0,0,0,0,0,0,0,0};
  if(inb){
    const float* xb = x + (size_t)b*CM*HW + ih*64 + iw;
    #pragma unroll 4
    for(int ic=0; ic<CM; ic++){
      float xv = xb[(size_t)ic*HW];
      #pragma unroll
      for(int j=0;j<8;j++){ acck[j] += xv*kw[(ocb+j)*CM+ic]; accv[j] += xv*vw[(ocb+j)*CM+ic]; }
    }
  }
  #pragma unroll
  for(int j=0;j<8;j++){
    size_t o = ((size_t)(b*CM+ocb+j))*PHW + p;
    k[o]=acck[j]; v[o]=accv[j];
  }
}

// ---------------- attention (q-conv fused) ----------------

__global__ void attn_kernel(const float* __restrict__ y1, const float* __restrict__ qw,
                            const float* __restrict__ k, const float* __restrict__ v,
                            const float* __restrict__ relh, const float* __restrict__ relw,
                            float* __restrict__ xatt){
  int t = blockIdx.x*256 + threadIdx.x;  // over B*CM*HW
  int p = t & 4095;
  int bc = t >> 12;       // b*128+c
  int c = bc & 127;
  int b = bc >> 7;
  int h = p>>6, w2 = p&63;
  // fused q = conv1x1(y_up, q_w) at this (b,c,p)
  int mi = ((p>>7)<<5) + ((p&63)>>1);    // (h/2)*32 + w/2
  const float* yb = y1 + (size_t)b*CM*HWy + mi;
  const float* wq = qw + c*CM;           // uniform per wave -> scalar loads
  float qv = 0.f;
  #pragma unroll 4
  for(int ic=0; ic<CM; ic++) qv += yb[(size_t)ic*HWy] * wq[ic];

  const float* kb = k + (size_t)bc*PHW;
  const float* vb = v + (size_t)bc*PHW;
  float lg[9], vv[9];
  #pragma unroll
  for(int ti=0; ti<3; ti++){
    #pragma unroll
    for(int tj=0; tj<3; tj++){
      int idx = (h+ti)*66 + (w2+tj);
      float rel = (c<64) ? relh[c*3+ti] : relw[(c-64)*3+tj];
      float kv = kb[idx] + rel;
      lg[ti*3+tj] = qv*kv;
      vv[ti*3+tj] = vb[idx];
    }
  }
  float mx = lg[0];
  #pragma unroll
  for(int i=1;i<9;i++) mx = fmaxf(mx, lg[i]);
  float s=0.f, o=0.f;
  #pragma unroll
  for(int i=0;i<9;i++){ float e = __expf(lg[i]-mx); s += e; o += e*vv[i]; }
  xatt[t] = o/s;
}

// ---------------- FFT helpers ----------------

template<int SIGN>
__device__ inline void dft8(const float2* a, float2* X){
  constexpr float C8[8] = {1.f,0.70710678118654752f,0.f,-0.70710678118654752f,
                           -1.f,-0.70710678118654752f,0.f,0.70710678118654752f};
  constexpr float S8[8] = {0.f,0.70710678118654752f,1.f,0.70710678118654752f,
                           0.f,-0.70710678118654752f,-1.f,-0.70710678118654752f};
  #pragma unroll
  for(int kk=0;kk<8;kk++){
    float xr=0.f, xi=0.f;
    #pragma unroll
    for(int n=0;n<8;n++){
      const int j=(n*kk)&7;
      const float wr = C8[j];
      const float wi = SIGN*S8[j];   // e^{SIGN*2pi i j/8}
      xr += a[n].x*wr - a[n].y*wi;
      xi += a[n].x*wi + a[n].y*wr;
    }
    X[kk].x=xr; X[kk].y=xi;
  }
}

// 64 lines x 64 elems, in-place in LDS. line l at img+l*lineStride, elem e at +e*elemStride.
// 8 threads per line (j), 32 lines per half-pass.
template<int SIGN>
__device__ inline void fft64_lds(float2* img, int lineStride, int elemStride){
  int j  = threadIdx.x >> 5;   // 0..7
  int ll = threadIdx.x & 31;
  #pragma unroll
  for(int half=0; half<2; half++){
    float2* L = img + (half*32 + ll)*lineStride;
    float2 a[8];
    #pragma unroll
    for(int n1=0;n1<8;n1++) a[n1] = L[(n1*8+j)*elemStride];
    float2 A[8];
    dft8<SIGN>(a, A);
    __syncthreads();           // all reads done before overwrite
    #pragma unroll
    for(int k1=0;k1<8;k1++){
      float ang = SIGN * (TWOPI/64.f) * (float)(j*k1);
      float sn, cs; __sincosf(ang, &sn, &cs);
      L[(k1*8+j)*elemStride] = make_float2(A[k1].x*cs - A[k1].y*sn, A[k1].x*sn + A[k1].y*cs);
    }
    __syncthreads();
    float2 bv[8];
    #pragma unroll
    for(int n2=0;n2<8;n2++) bv[n2] = L[(j*8+n2)*elemStride];
    float2 Y[8];
    dft8<SIGN>(bv, Y);
    __syncthreads();
    #pragma unroll
    for(int k2=0;k2<8;k2++) L[(j + 8*k2)*elemStride] = Y[k2];
    __syncthreads();
  }
}

// whole-image forward 2D FFT: real xatt (64x64) -> complex E, scale 1/64. One block per (b,c).
__global__ void fft2d_fwd(const float* __restrict__ xatt, float2* __restrict__ E){
  __shared__ float2 img[64*65];
  int bc = blockIdx.x;
  const float* src = xatt + (size_t)bc*HW;
  for(int s=threadIdx.x; s<1024; s+=256){
    float4 t = ((const float4*)src)[s];
    int idx = s*4; int r = idx>>6, c = idx&63;
    float2* d = img + r*65 + c;
    d[0]=make_float2(t.x,0.f); d[1]=make_float2(t.y,0.f);
    d[2]=make_float2(t.z,0.f); d[3]=make_float2(t.w,0.f);
  }
  __syncthreads();
  fft64_lds<-1>(img, 65, 1);   // rows
  fft64_lds<-1>(img, 1, 65);   // cols
  float2* dst = E + (size_t)bc*HW;
  for(int s=threadIdx.x; s<2048; s+=256){
    int idx = s*2; int r = idx>>6, c = idx&63;
    float2 v0 = img[r*65+c], v1 = img[r*65+c+1];
    ((float4*)dst)[s] = make_float4(v0.x*0.015625f, v0.y*0.015625f, v1.x*0.015625f, v1.y*0.015625f);
  }
}

// whole-image inverse 2D FFT: complex F -> real G, scale 1/64. One block per (kb,o).
__global__ void fft2d_inv(const float2* __restrict__ F, float* __restrict__ G){
  __shared__ float2 img[64*65];
  int bc = blockIdx.x;
  const float2* src = F + (size_t)bc*HW;
  for(int s=threadIdx.x; s<2048; s+=256){
    float4 t = ((const float4*)src)[s];
    int idx = s*2; int r = idx>>6, c = idx&63;
    img[r*65+c]   = make_float2(t.x,t.y);
    img[r*65+c+1] = make_float2(t.z,t.w);
  }
  __syncthreads();
  fft64_lds<1>(img, 65, 1);
  fft64_lds<1>(img, 1, 65);
  float* dst = G + (size_t)bc*HW;
  for(int s=threadIdx.x; s<1024; s+=256){
    int idx = s*4; int r = idx>>6, c = idx&63;
    float2* p2 = img + r*65 + c;
    ((float4*)dst)[s] = make_float4(p2[0].x*0.015625f, p2[1].x*0.015625f,
                                    p2[2].x*0.015625f, p2[3].x*0.015625f);
  }
}

// 128-pt FFT along channel axis, in-place; 16 lines/block x 16 threads
template<int SIGN>
__global__ void fft128_kernel(float* data, float scale){
  __shared__ float2 tmp[16][129];
  int ll = threadIdx.x & 15;
  int j  = threadIdx.x >> 4;   // n2 = 0..15
  int l = blockIdx.x*16 + ll;  // (b, hf*64+wf)
  int b = l >> 12;
  int rem = l & 4095;
  size_t base = (size_t)b*CM*HW + rem;
  float2* cd = (float2*)data;
  float2 a[8];
  #pragma unroll
  for(int n1=0;n1<8;n1++) a[n1] = cd[base + (size_t)(16*n1 + j)*HW];
  float2 A[8];
  dft8<SIGN>(a, A);
  #pragma unroll
  for(int k1=0;k1<8;k1++){
    float ang = SIGN*(TWOPI/128.f)*(float)(j*k1);
    float sn,cs; __sincosf(ang,&sn,&cs);
    tmp[ll][k1*16 + j] = make_float2(A[k1].x*cs - A[k1].y*sn, A[k1].x*sn + A[k1].y*cs);
  }
  __syncthreads();
  int k1 = j & 7, half = j >> 3;
  float2 bv[16];
  #pragma unroll
  for(int n2=0;n2<16;n2++) bv[n2] = tmp[ll][k1*16+n2];
  #pragma unroll
  for(int kk=0;kk<8;kk++){
    int k2 = half*8 + kk;
    float xr=0.f, xi=0.f;
    #pragma unroll
    for(int n2=0;n2<16;n2++){
      float ang = SIGN*(TWOPI/16.f)*(float)((n2*k2)&15);
      float sn,cs; __sincosf(ang,&sn,&cs);
      xr += bv[n2].x*cs - bv[n2].y*sn;
      xi += bv[n2].x*sn + bv[n2].y*cs;
    }
    cd[base + (size_t)(k1 + 8*k2)*HW] = make_float2(xr*scale, xi*scale);
  }
}

// ---------------- channel-mixing einsum (+inline batch FFT4 + mask) ----------------
// OutF[kb,o,f] = sum_i FFT4_b(E[b,i,f])[kb] * w1[i,o,f]
// 1D grid of 512: f-tile = L%64 (so the 8 o-blocks of one f-tile share an XCD L2),
// o-block = L/64. Padded LDS: per (ii,kb) row = 16 pairs of float4 + 1 pad float4
// each (48 float4 = 768B); thread fl reads slots 3*fl,3*fl+1 -> 12*fl words mod 32
// -> 2-way bank aliasing only (free).
__global__ __launch_bounds__(256, 2)
void einsum_kernel(const float2* __restrict__ Xf, const float* __restrict__ w1r,
                   const float* __restrict__ w1i, float2* __restrict__ OutF){
  int L = blockIdx.x;
  int fbase = (L & 63) * 64;
  int obase = (L >> 6) * 16;
  int fl = threadIdx.x & 15;      // 4 consecutive f each
  int ol = threadIdx.x >> 4;      // 0..15 o within tile
  __shared__ float4 Xs[1536];     // [ (ii*4+kb) ][48], 24 KB
  float2* Xs2 = (float2*)Xs;
  float accr[4][4], acci[4][4];   // [ff][kb]
  #pragma unroll
  for(int a1=0;a1<4;a1++)
    #pragma unroll
    for(int a2=0;a2<4;a2++){ accr[a1][a2]=0.f; acci[a1][a2]=0.f; }

  for(int ic=0; ic<CM; ic+=8){
    __syncthreads();
    for(int s=threadIdx.x; s<512; s+=256){
      int ii = s>>6, fo = s&63;
      size_t base = ((size_t)(ic+ii))*HW + fbase + fo;
      float2 x0 = Xf[base];
      float2 x1 = Xf[base +  524288];
      float2 x2 = Xf[base + 1048576];
      float2 x3 = Xf[base + 1572864];
      int rb = (ii*4)*96 + (fo>>2)*6 + (fo&3);
      Xs2[rb      ] = make_float2(x0.x+x1.x+x2.x+x3.x,  x0.y+x1.y+x2.y+x3.y);
      Xs2[rb +  96] = make_float2(x0.x+x1.y-x2.x-x3.y,  x0.y-x1.x-x2.y+x3.x);
      Xs2[rb + 192] = make_float2(x0.x-x1.x+x2.x-x3.x,  x0.y-x1.y+x2.y-x3.y);
      Xs2[rb + 288] = make_float2(x0.x-x1.y-x2.x+x3.y,  x0.y+x1.x-x2.y-x3.x);
    }
    __syncthreads();
    #pragma unroll
    for(int ii=0; ii<8; ii++){
      size_t wbase = ((size_t)((ic+ii)*CM + obase + ol))*HW + fbase + fl*4;
      float4 wr = *(const float4*)(w1r + wbase);
      float4 wi = *(const float4*)(w1i + wbase);
      #pragma unroll
      for(int kb=0; kb<4; kb++){
        const float4* xrow = Xs + (ii*4+kb)*48;
        float4 xa = xrow[fl*3], xb = xrow[fl*3+1];
        accr[0][kb] += xa.x*wr.x - xa.y*wi.x;  acci[0][kb] += xa.x*wi.x + xa.y*wr.x;
        accr[1][kb] += xa.z*wr.y - xa.w*wi.y;  acci[1][kb] += xa.z*wi.y + xa.w*wr.y;
        accr[2][kb] += xb.x*wr.z - xb.y*wi.z;  acci[2][kb] += xb.x*wi.z + xb.y*wr.z;
        accr[3][kb] += xb.z*wr.w - xb.w*wi.w;  acci[3][kb] += xb.z*wi.w + xb.w*wr.w;
      }
    }
  }
  // mask + packed writes (32B contiguous per (kb))
  int f0 = fbase + fl*4;
  float msk[4];
  #pragma unroll
  for(int ff=0; ff<4; ff++){
    int f = f0+ff, hf = f>>6, wf = f&63;
    msk[ff] = ((hf<3||hf>60)&&(wf<3||wf>60)) ? 0.f : 1.f;
  }
  int o = obase + ol;
  #pragma unroll
  for(int kb=0; kb<4; kb++){
    float4* dst = (float4*)(OutF + ((size_t)(kb*CM+o))*HW + f0);
    dst[0] = make_float4(accr[0][kb]*msk[0], acci[0][kb]*msk[0],
                         accr[1][kb]*msk[1], acci[1][kb]*msk[1]);
    dst[1] = make_float4(accr[2][kb]*msk[2], acci[2][kb]*msk[2],
                         accr[3][kb]*msk[3], acci[3][kb]*msk[3]);
  }
}

// ---------------- final combine: w0 conv + blend + bn2 + relu ----------------
// LDS-staged xatt: block = (p-tile 256, oc-tile 16, b); xatt chunk in LDS reused by 16 oc.
__global__ __launch_bounds__(256, 2)
void final_kernel(const float* __restrict__ G, const float* __restrict__ xatt,
                  const float* __restrict__ w0, const float* __restrict__ w0b,
                  const float* __restrict__ r1p, const float* __restrict__ r2p,
                  const float* __restrict__ g2, const float* __restrict__ b2,
                  const float* __restrict__ m2, const float* __restrict__ v2,
                  float* __restrict__ yout){
  int tid = threadIdx.x;
  int p = blockIdx.x*256 + tid;
  int ocb = blockIdx.y*16;
  int b = blockIdx.z;
  __shared__ float xs[32][256];   // 32 KB
  float acc[16];
  #pragma unroll
  for(int j=0;j<16;j++) acc[j]=0.f;
  const float* xb = xatt + (size_t)b*CM*HW + p;
  for(int chunk=0; chunk<4; chunk++){
    __syncthreads();
    #pragma unroll
    for(int r=0;r<32;r++) xs[r][tid] = xb[(size_t)(chunk*32+r)*HW];
    __syncthreads();
    #pragma unroll
    for(int r=0;r<32;r++){
      float xv = xs[r][tid];
      int ic = chunk*32 + r;
      #pragma unroll
      for(int j=0;j<16;j++) acc[j] += xv * w0[(ocb+j)*CM + ic];
    }
  }
  float r1 = r1p[0], r2 = r2p[0];
  #pragma unroll
  for(int j=0;j<16;j++){
    int oc = ocb+j;
    float fam = r1 * G[((size_t)(b*CM+oc))*HW + p] + r2*(acc[j] + w0b[oc]);
    float s = g2[oc]*rsqrtf(v2[oc]+EPSF);
    float bi = b2[oc] - m2[oc]*s;
    float val = fam*s + bi;
    yout[((size_t)(b*CM+oc))*HW + p] = val>0.f?val:0.f;
  }
}

extern "C" void kernel_launch(void* const* d_in, const int* in_sizes, int n_in,
                              void* d_out, int out_size, void* d_ws, size_t ws_size,
                              hipStream_t stream){
  const float* x       = (const float*)d_in[0];
  const float* y       = (const float*)d_in[1];
  const float* conv1_w = (const float*)d_in[2];
  const float* bn1_g   = (const float*)d_in[3];
  const float* bn1_b   = (const float*)d_in[4];
  const float* bn1_m   = (const float*)d_in[5];
  const float* bn1_v   = (const float*)d_in[6];
  const float* q_w     = (const float*)d_in[7];
  const float* k_w     = (const float*)d_in[8];
  const float* v_w     = (const float*)d_in[9];
  const float* rel_h   = (const float*)d_in[10];
  const float* rel_w   = (const float*)d_in[11];
  const float* rate1   = (const float*)d_in[12];
  const float* rate2   = (const float*)d_in[13];
  const float* w1r     = (const float*)d_in[14];
  const float* w1i     = (const float*)d_in[15];
  const float* w0_w    = (const float*)d_in[16];
  const float* w0_b    = (const float*)d_in[17];
  const float* bn2_g   = (const float*)d_in[18];
  const float* bn2_b   = (const float*)d_in[19];
  const float* bn2_m   = (const float*)d_in[20];
  const float* bn2_v   = (const float*)d_in[21];
  (void)in_sizes; (void)n_in; (void)out_size; (void)ws_size;

  char* ws = (char*)d_ws;
  // phase-1 (dead after attn)
  float* Y1 = (float*)(ws + 0);                 // 2 MB
  float* K  = (float*)(ws + 2097152);           // 8.92 MB
  float* V  = (float*)(ws + 11018240);          // 8.92 MB
  // phase-2
  float2* E = (float2*)(ws + 0);                // 16 MB (written after attn completes)
  float2* F = (float2*)(ws + 16777216);         // 16 MB  -> peak ws = 32 MB
  float*  G = (float*)(ws + 0);                 // 8 MB over dead E

  float* yout = (float*)d_out;
  float* xatt = (float*)d_out + 2097152;

  conv1_kernel<<<dim3(4,16,BB),256,0,stream>>>(y, conv1_w, bn1_g,bn1_b,bn1_m,bn1_v, Y1);
  kvconv_kernel<<<dim3(18,16,BB),256,0,stream>>>(x, k_w, v_w, K, V);
  attn_kernel<<<dim3(8192),256,0,stream>>>(Y1, q_w, K, V, rel_h, rel_w, xatt);

  fft2d_fwd<<<dim3(512),256,0,stream>>>(xatt, E);
  fft128_kernel<-1><<<dim3(1024),256,0,stream>>>((float*)E, 0.044194173824159216f);
  einsum_kernel<<<dim3(512),256,0,stream>>>(E, w1r, w1i, F);
  fft2d_inv<<<dim3(512),256,0,stream>>>(F, G);

  final_kernel<<<dim3(16,8,BB),256,0,stream>>>(G, xatt, w0_w, w0_b, rate1, rate2,
                                               bn2_g,bn2_b,bn2_m,bn2_v, yout);
}